// Round 6
// baseline (340.066 us; speedup 1.0000x reference)
//
#include <hip/hip_runtime.h>

// Chamfer loss: pred [8,4096,3] f32, gt [8,4096,3] f32 -> scalar f32.
//
// ROUND-11 = MEASUREMENT ROUND (intentionally slow; revert next round).
// Session ledger: R5 (1/4 VALU) -7us, R6 (1/4 MFMA) -7us, R9 (fusion) gaps
// only ~5us, R10 (2x occupancy) +-0. Reconstructed A+B ~= 39-43us across
// three structures; issue/latency models say A~5, B~7. Attribution is
// broken and both kernels hide below the ~40us fill dispatches in the
// rocprof top-5. Fix attribution: amplify A x8 and B x16 via idempotent
// rep loops (min-reduction and radix-select recomputation are idempotent;
// finalization gated on last rep; asm-volatile opacity stops CSE across
// reps). Per-rep arithmetic byte-identical to R10 (passed, absmax 0.0).
// Read: visible_A/8 = A_true, visible_B/16 = B_true, plus per-kernel
// MfmaUtil/VALUBusy/Occupancy at amplified scale.

#define BATCH 8
#define NPTS  4096
#define NPTS2 2048             // g-points per A-block (half the set)
#define TOPK  2048
#define BT    256
#define NROW  (2 * BATCH)      // 16 rows = b*2+dir

#define REPS_A 8
#define REPS_B 16

typedef _Float16 half8 __attribute__((ext_vector_type(8)));
typedef float floatx16 __attribute__((ext_vector_type(16)));

static __device__ inline unsigned pack_h2(float a, float b) {
  unsigned short ua = __builtin_bit_cast(unsigned short, (_Float16)a);
  unsigned short ub = __builtin_bit_cast(unsigned short, (_Float16)b);
  return (unsigned)ua | ((unsigned)ub << 16);
}

// ---------------- Kernel A: min squared distance via 32x32x16 MFMA ---------
// grid (64, 2, 16) = 2048 blocks -> 8 blocks/CU. Body repeated reps times
// (idempotent); only structure change vs R10 is the rep loop.
__global__ __launch_bounds__(BT, 8) void nn_min_kernel(
    const float* __restrict__ pred, const float* __restrict__ gt,
    float* __restrict__ minsq, float* __restrict__ out, int reps) {
  const int row  = blockIdx.z;         // b*2 + dir
  const int half = blockIdx.y;         // which 2048 g-points
  const int b    = row >> 1;
  const int dir  = row & 1;
  const float* q = (dir == 0 ? pred : gt) + (size_t)b * NPTS * 3;
  const float* g = (dir == 0 ? gt : pred) + (size_t)b * NPTS * 3 +
                   (size_t)half * NPTS2 * 3;

  __shared__ uint2 gsh[NPTS2 + 32];    // f16x4 (-2x,-2y,-2z,|g|^2) + zero slots
  __shared__ float comb[4][2][16];     // per-wave per-subhalf partial minima
  const int tid = threadIdx.x;

  for (int rep = 0; rep < reps; ++rep) {
    __syncthreads();                   // gsh/comb safe vs previous rep readers

    // Stage 2048 g-points: 4 pts/thread/chunk via 3x float4 loads -> 2x b128.
#pragma unroll
    for (int c = 0; c < 2; c++) {
      int p = c * 1024 + tid * 4;                      // 4 consecutive points
      const float4* src = (const float4*)(g + 3 * p);  // 12 floats, 16B-aligned
      float4 f0 = src[0], f1 = src[1], f2 = src[2];
      float x0 = f0.x, y0 = f0.y, z0 = f0.z;
      float x1 = f0.w, y1 = f1.x, z1 = f1.y;
      float x2 = f1.z, y2 = f1.w, z2 = f2.x;
      float x3 = f2.y, y3 = f2.z, z3 = f2.w;
      uint2 u0 = make_uint2(pack_h2(-2.f * x0, -2.f * y0),
                            pack_h2(-2.f * z0, x0 * x0 + y0 * y0 + z0 * z0));
      uint2 u1 = make_uint2(pack_h2(-2.f * x1, -2.f * y1),
                            pack_h2(-2.f * z1, x1 * x1 + y1 * y1 + z1 * z1));
      uint2 u2 = make_uint2(pack_h2(-2.f * x2, -2.f * y2),
                            pack_h2(-2.f * z2, x2 * x2 + y2 * y2 + z2 * z2));
      uint2 u3 = make_uint2(pack_h2(-2.f * x3, -2.f * y3),
                            pack_h2(-2.f * z3, x3 * x3 + y3 * y3 + z3 * z3));
      *(uint4*)&gsh[p]     = make_uint4(u0.x, u0.y, u1.x, u1.y);
      *(uint4*)&gsh[p + 2] = make_uint4(u2.x, u2.y, u3.x, u3.y);
    }
    if (tid < 32) gsh[NPTS2 + tid] = make_uint2(0u, 0u);
    if (tid == 0 && blockIdx.x == 0 && blockIdx.y == 0 && blockIdx.z == 0 &&
        rep == 0)
      out[0] = 0.0f;                   // select accumulates into out

    const int lane = tid & 63;
    const int wave = tid >> 6;
    const int col  = lane & 31;        // n (g) index within tile
    const int hi   = lane >> 5;        // k-half / row-half selector
    const int qg   = blockIdx.x * 2 + (wave >> 1);   // q-group of 32
    const int gh   = wave & 1;                       // g-sub-half (1024 pts)
    const int q0   = qg * 32;

    // A fragment: lane l<32 holds A[m=l][k=0..7] = (qx,qy,qz,1,0,0,0,0).
    half8 afrag = {};
    float qnv = 0.0f;
    if (lane < 32) {
      int qi = q0 + lane;
      float qx = q[3 * qi + 0], qy = q[3 * qi + 1], qz = q[3 * qi + 2];
      // opacity: prevent CSE of the q-dependent chain across reps
      asm volatile("" : "+v"(qx), "+v"(qy), "+v"(qz));
      qnv = qx * qx + qy * qy + qz * qz;
      afrag[0] = (_Float16)qx;
      afrag[1] = (_Float16)qy;
      afrag[2] = (_Float16)qz;
      afrag[3] = (_Float16)1.0f;
    }
    __syncthreads();

    const char* lds = (const char*)gsh;
    int off  = (lane < 32) ? (gh * 8192 + col * 8) : (NPTS2 * 8 + col * 8);
    int step = (lane < 32) ? 32 * 8 : 0;

    floatx16 macc, zc;
#pragma unroll
    for (int i = 0; i < 16; i++) { macc[i] = 3.0e38f; zc[i] = 0.0f; }

    // 32 g-tiles of 32, processed in pairs -> v_min3 fusion on accumulate.
#pragma unroll 4
    for (int t = 0; t < 16; t++) {
      uint2 w0 = *(const uint2*)(lds + off);
      uint2 w1 = *(const uint2*)(lds + off + step);
      off += 2 * step;
      union { int4 i; half8 h; } b0, b1;
      b0.i = make_int4((int)w0.x, (int)w0.y, 0, 0);
      b1.i = make_int4((int)w1.x, (int)w1.y, 0, 0);
      floatx16 r0 = __builtin_amdgcn_mfma_f32_32x32x16_f16(afrag, b0.h, zc, 0, 0, 0);
      floatx16 r1 = __builtin_amdgcn_mfma_f32_32x32x16_f16(afrag, b1.h, zc, 0, 0, 0);
#pragma unroll
      for (int i = 0; i < 16; i++)
        macc[i] = fminf(fminf(macc[i], r0[i]), r1[i]);
    }

    // C/D layout: col=lane&31 (g), row=(reg&3)+8*(reg>>2)+4*hi (q).
#pragma unroll
    for (int mask = 1; mask < 32; mask <<= 1) {
#pragma unroll
      for (int i = 0; i < 16; i++)
        macc[i] = fminf(macc[i], __shfl_xor(macc[i], mask));
    }

    // Exact fp32 |q|^2 per output row, fetched by in-wave shuffle.
    float qnr[16];
#pragma unroll
    for (int r = 0; r < 16; r++)
      qnr[r] = __shfl(qnv, (r & 3) + 8 * (r >> 2) + 4 * hi);

    if (col == 0) {
#pragma unroll
      for (int i = 0; i < 16; i += 4)
        *(float4*)&comb[wave][hi][i] =
            make_float4(macc[i], macc[i + 1], macc[i + 2], macc[i + 3]);
    }
    __syncthreads();

    // Even waves merge the two g-sub-halves of their q-group, store 32 rows.
    if ((wave & 1) == 0 && col == 0) {
      float* dst = minsq + ((size_t)row * 2 + half) * NPTS + q0;
#pragma unroll
      for (int rq = 0; rq < 4; rq++) {
        float4 outv;
#pragma unroll
        for (int j = 0; j < 4; j++) {
          int r = rq * 4 + j;
          float v = fminf(comb[wave][hi][r], comb[wave + 1][hi][r]);
          ((float*)&outv)[j] = fmaxf(qnr[r] + v, 0.0f);
        }
        *(float4*)(dst + rq * 8 + hi * 4) = outv;
      }
    }
  }
}

// ---------------- Kernel B: min-combine halves, sqrt, mean, top-k ----------
// 15-round radix on bits 30..16; body repeated reps times (idempotent).
__global__ __launch_bounds__(BT) void select_kernel(
    const float* __restrict__ minsq, float* __restrict__ out, int reps) {
  const int row = blockIdx.x;                // 0..15 = b*2+dir
  const float* h0 = minsq + (size_t)row * 2 * NPTS;
  const float* h1 = h0 + NPTS;
  const int tid = threadIdx.x;

  __shared__ float sf[4];
  __shared__ int   si[4];

  const int PER = NPTS / BT;  // 16 values per thread

  for (int rep = 0; rep < reps; ++rep) {
    __syncthreads();                   // sf/si safe vs previous rep readers

    float d[PER];
    float sum_all = 0.0f;
#pragma unroll
    for (int j = 0; j < PER; j++) {
      int idx = tid + BT * j;
      float m = fminf(h0[idx], h1[idx]);
      asm volatile("" : "+v"(m));      // opacity: force per-rep recompute
      float v = sqrtf(m);
      d[j] = v;
      sum_all += v;
    }

    // block float sum of sum_all
    {
      float v = sum_all;
      for (int off = 32; off > 0; off >>= 1) v += __shfl_down(v, off);
      if ((tid & 63) == 0) sf[tid >> 6] = v;
      __syncthreads();
      sum_all = sf[0] + sf[1] + sf[2] + sf[3];
      __syncthreads();
    }

    // radix-select the TOPK-th largest over top-15 float bits (nonneg)
    unsigned sel = 0u;
    for (int bit = 30; bit >= 16; --bit) {
      unsigned cand = sel | (1u << bit);
      int c = 0;
#pragma unroll
      for (int j = 0; j < PER; j++) c += (__float_as_uint(d[j]) >= cand) ? 1 : 0;
      for (int off = 32; off > 0; off >>= 1) c += __shfl_down(c, off);
      if ((tid & 63) == 0) si[tid >> 6] = c;
      __syncthreads();
      int total = si[0] + si[1] + si[2] + si[3];
      __syncthreads();
      if (total >= TOPK) sel = cand;
    }

    // sum of strictly-greater values + count (full-precision compare)
    int cgt = 0;
    float sgt = 0.0f;
#pragma unroll
    for (int j = 0; j < PER; j++) {
      if (__float_as_uint(d[j]) > sel) { cgt++; sgt += d[j]; }
    }
    {
      float v = sgt;
      for (int off = 32; off > 0; off >>= 1) v += __shfl_down(v, off);
      if ((tid & 63) == 0) sf[tid >> 6] = v;
      int c = cgt;
      for (int off = 32; off > 0; off >>= 1) c += __shfl_down(c, off);
      if ((tid & 63) == 0) si[tid >> 6] = c;
      __syncthreads();
      sgt = sf[0] + sf[1] + sf[2] + sf[3];
      cgt = si[0] + si[1] + si[2] + si[3];
    }

    if (tid == 0 && rep == reps - 1) {
      float kth = __uint_as_float(sel);
      float topk_sum = sgt + (float)(TOPK - cgt) * kth;
      float rowval = sum_all / (float)NPTS + 3.0f * (topk_sum / (float)TOPK);
      atomicAdd(out, rowval * (1.0f / (float)BATCH));
    }
  }
}

extern "C" void kernel_launch(void* const* d_in, const int* in_sizes, int n_in,
                              void* d_out, int out_size, void* d_ws, size_t ws_size,
                              hipStream_t stream) {
  const float* pred = (const float*)d_in[0];
  const float* gt   = (const float*)d_in[1];
  float* out = (float*)d_out;
  float* minsq = (float*)d_ws;   // [NROW][2][NPTS] = 512 KB

  dim3 gridA(NPTS / 64, 2, NROW);   // 2048 blocks -> 8/CU
  nn_min_kernel<<<gridA, BT, 0, stream>>>(pred, gt, minsq, out, REPS_A);
  select_kernel<<<NROW, BT, 0, stream>>>(minsq, out, REPS_B);
}

// Round 7
// 82.528 us; speedup vs baseline: 4.1206x; 4.1206x over previous
//
#include <hip/hip_runtime.h>

// Chamfer loss: pred [8,4096,3] f32, gt [8,4096,3] f32 -> scalar f32.
//
// R11 measurement: A_true=19.4us (VALUBusy 48.5% -> ~1400 VALU inst/wave,
// MfmaUtil 18.4% = 3.4us matrix-pipe, Occ 71.6%, conflicts negligible),
// B_true~9us, inter-dispatch gaps ~15-20us, fill floor ~40-45us.
// A is VALU-issue-bound + 50% stalls (fminf lowering, 160-op ds_bpermute
// butterfly epilogue, MFMA->min chains). R12 fixes:
//  1. main-loop accumulate = inline-asm v_min3_f32 (8 VALU/MFMA, was 32+)
//  2. epilogue: LDS-transpose (union-overlaid on dead g-buffer, padded
//     stride 68 floats; writes 2-way=free) + register tree + 1 shfl +
//     coalesced store with own-lane exact fp32 qn. Replaces butterfly,
//     qnr shuffles, comb buffer.
//  3. ds_read prefetch 1 iter ahead (t=15 prefetch lands in zero region).
//  4. B at block=1024 (PER=4) to cut the 15 serial radix rounds.

#define BATCH 8
#define NPTS  4096
#define NPTS2 2048             // g-points per A-block (half the set)
#define TOPK  2048
#define BT    256
#define BTB   1024
#define NROW  (2 * BATCH)      // 16 rows = b*2+dir

typedef _Float16 half8 __attribute__((ext_vector_type(8)));
typedef float floatx16 __attribute__((ext_vector_type(16)));

static __device__ inline unsigned pack_h2(float a, float b) {
  unsigned short ua = __builtin_bit_cast(unsigned short, (_Float16)a);
  unsigned short ub = __builtin_bit_cast(unsigned short, (_Float16)b);
  return (unsigned)ua | ((unsigned)ub << 16);
}

static __device__ inline float amin3(float a, float b, float c) {
  float d;
  asm("v_min3_f32 %0, %1, %2, %3" : "=v"(d) : "v"(a), "v"(b), "v"(c));
  return d;
}

// ---------------- Kernel A: min squared distance via 32x32x16 MFMA ---------
// grid (64, 2, 16) = 2048 blocks -> 8 blocks/CU. Block: 64 q x 2048 g.
// Wave: 32 q x 1024 g (16 paired iterations).
__global__ __launch_bounds__(BT, 8) void nn_min_kernel(
    const float* __restrict__ pred, const float* __restrict__ gt,
    float* __restrict__ minsq, float* __restrict__ out) {
  const int row  = blockIdx.z;         // b*2 + dir
  const int half = blockIdx.y;         // which 2048 g-points
  const int b    = row >> 1;
  const int dir  = row & 1;
  const float* q = (dir == 0 ? pred : gt) + (size_t)b * NPTS * 3;
  const float* g = (dir == 0 ? gt : pred) + (size_t)b * NPTS * 3 +
                   (size_t)half * NPTS2 * 3;

  // gsh: staged f16x4 g-points + 32 zero slots (16640 B), dead after main
  // loop. scr: per-pair transpose scratch [pair][q 0..31][col 0..63, pad->68]
  // (17408 B). Union-overlaid; separated by a barrier.
  union __align__(16) SharedU {
    uint2 gsh[NPTS2 + 32];
    float scr[2][32][68];
  };
  __shared__ SharedU sh;
  const int tid = threadIdx.x;

  // Stage 2048 g-points: 4 pts/thread/chunk via 3x float4 loads -> 2x b128.
#pragma unroll
  for (int c = 0; c < 2; c++) {
    int p = c * 1024 + tid * 4;                      // 4 consecutive points
    const float4* src = (const float4*)(g + 3 * p);  // 12 floats, 16B-aligned
    float4 f0 = src[0], f1 = src[1], f2 = src[2];
    float x0 = f0.x, y0 = f0.y, z0 = f0.z;
    float x1 = f0.w, y1 = f1.x, z1 = f1.y;
    float x2 = f1.z, y2 = f1.w, z2 = f2.x;
    float x3 = f2.y, y3 = f2.z, z3 = f2.w;
    uint2 u0 = make_uint2(pack_h2(-2.f * x0, -2.f * y0),
                          pack_h2(-2.f * z0, x0 * x0 + y0 * y0 + z0 * z0));
    uint2 u1 = make_uint2(pack_h2(-2.f * x1, -2.f * y1),
                          pack_h2(-2.f * z1, x1 * x1 + y1 * y1 + z1 * z1));
    uint2 u2 = make_uint2(pack_h2(-2.f * x2, -2.f * y2),
                          pack_h2(-2.f * z2, x2 * x2 + y2 * y2 + z2 * z2));
    uint2 u3 = make_uint2(pack_h2(-2.f * x3, -2.f * y3),
                          pack_h2(-2.f * z3, x3 * x3 + y3 * y3 + z3 * z3));
    *(uint4*)&sh.gsh[p]     = make_uint4(u0.x, u0.y, u1.x, u1.y);
    *(uint4*)&sh.gsh[p + 2] = make_uint4(u2.x, u2.y, u3.x, u3.y);
  }
  if (tid < 32) sh.gsh[NPTS2 + tid] = make_uint2(0u, 0u);
  if (tid == 0 && blockIdx.x == 0 && blockIdx.y == 0 && blockIdx.z == 0)
    out[0] = 0.0f;                     // select accumulates into out

  const int lane = tid & 63;
  const int wave = tid >> 6;
  const int col  = lane & 31;          // n (g) index within tile
  const int hi   = lane >> 5;          // k-half / row-half selector
  const int pair = wave >> 1;                      // q-group pair id
  const int qg   = blockIdx.x * 2 + pair;          // q-group of 32
  const int gh   = wave & 1;                       // g-sub-half (1024 pts)
  const int q0   = qg * 32;

  // A fragment: lane l<32 holds A[m=l][k=0..7] = (qx,qy,qz,1,0,0,0,0).
  half8 afrag = {};
  float qnv = 0.0f;
  if (lane < 32) {
    int qi = q0 + lane;
    float qx = q[3 * qi + 0], qy = q[3 * qi + 1], qz = q[3 * qi + 2];
    qnv = qx * qx + qy * qy + qz * qz;
    afrag[0] = (_Float16)qx;
    afrag[1] = (_Float16)qy;
    afrag[2] = (_Float16)qz;
    afrag[3] = (_Float16)1.0f;
  }
  __syncthreads();

  const char* lds = (const char*)sh.gsh;
  int off  = (lane < 32) ? (gh * 8192 + col * 8) : (NPTS2 * 8 + col * 8);
  int step = (lane < 32) ? 32 * 8 : 0;

  float macc[16];
  floatx16 zc;
#pragma unroll
  for (int i = 0; i < 16; i++) { macc[i] = 3.0e38f; zc[i] = 0.0f; }

  // 32 g-tiles of 32, paired; prefetch 1 iter ahead (t=15 prefetch lands
  // in the zero region / gh=1 region -> always in-bounds, value unused).
  uint2 w0 = *(const uint2*)(lds + off);
  uint2 w1 = *(const uint2*)(lds + off + step);
#pragma unroll 4
  for (int t = 0; t < 16; t++) {
    off += 2 * step;
    uint2 nw0 = *(const uint2*)(lds + off);
    uint2 nw1 = *(const uint2*)(lds + off + step);
    union { int4 i; half8 h; } b0, b1;
    b0.i = make_int4((int)w0.x, (int)w0.y, 0, 0);
    b1.i = make_int4((int)w1.x, (int)w1.y, 0, 0);
    floatx16 r0 = __builtin_amdgcn_mfma_f32_32x32x16_f16(afrag, b0.h, zc, 0, 0, 0);
    floatx16 r1 = __builtin_amdgcn_mfma_f32_32x32x16_f16(afrag, b1.h, zc, 0, 0, 0);
#pragma unroll
    for (int i = 0; i < 16; i++) {
      float a = r0[i], c = r1[i];
      macc[i] = amin3(macc[i], a, c);
    }
    w0 = nw0; w1 = nw1;
  }

  // -------- epilogue: LDS transpose + register tree (no butterfly) --------
  __syncthreads();                     // all main loops done; gsh dead

  // C/D layout: col=lane&31 (g), q-row=(i&3)+8*(i>>2)+4*hi. Write the
  // pair's 32x64 min-matrix: scr[pair][qrow][col + 32*gh]. Banks: (4q+c)%32,
  // rows q and q+4 disjoint -> 2 touches/bank = free.
#pragma unroll
  for (int i = 0; i < 16; i++) {
    int qrow = (i & 3) + 8 * (i >> 2) + 4 * hi;
    sh.scr[pair][qrow][col + 32 * gh] = macc[i];
  }
  __syncthreads();

  // Even wave of each pair reduces its 32 rows over 64 cols and stores.
  if (gh == 0) {
    const int r = lane & 31;           // q-row handled by this lane
    const int h = lane >> 5;           // which 32-col half
    const float4* rp = (const float4*)&sh.scr[pair][r][h * 32];
    float4 m4 = rp[0];
#pragma unroll
    for (int k = 1; k < 8; k++) {
      float4 a = rp[k];
      m4.x = fminf(m4.x, a.x); m4.y = fminf(m4.y, a.y);
      m4.z = fminf(m4.z, a.z); m4.w = fminf(m4.w, a.w);
    }
    float m = fminf(amin3(m4.x, m4.y, m4.z), m4.w);
    m = fminf(m, __shfl_xor(m, 32));   // combine the two col-halves
    if (h == 0) {
      // lane r owns q-row r: qnv is this lane's own exact fp32 |q|^2
      minsq[((size_t)row * 2 + half) * NPTS + q0 + r] = fmaxf(qnv + m, 0.0f);
    }
  }
}

// ---------------- Kernel B: min-combine halves, sqrt, mean, top-k ----------
// block = 1024 (PER=4); 15-round radix on bits 30..16 (truncated-pivot-exact
// tie formula). 16 blocks, one per row.
__global__ __launch_bounds__(BTB) void select_kernel(
    const float* __restrict__ minsq, float* __restrict__ out) {
  const int row = blockIdx.x;                // 0..15 = b*2+dir
  const float* h0 = minsq + (size_t)row * 2 * NPTS;
  const float* h1 = h0 + NPTS;
  const int tid = threadIdx.x;

  __shared__ float sf[16];
  __shared__ int   si[16];
  __shared__ float s_fbc;
  __shared__ int   s_ibc;

  const int PER = NPTS / BTB;  // 4 values per thread
  float d[PER];
  float sum_all = 0.0f;
#pragma unroll
  for (int j = 0; j < PER; j++) {
    int idx = tid + BTB * j;
    float v = sqrtf(fminf(h0[idx], h1[idx]));
    d[j] = v;
    sum_all += v;
  }

  // block float sum of sum_all
  {
    float v = sum_all;
    for (int off = 32; off > 0; off >>= 1) v += __shfl_down(v, off);
    if ((tid & 63) == 0) sf[tid >> 6] = v;
    __syncthreads();
    if (tid == 0) {
      float s = 0.0f;
#pragma unroll
      for (int k = 0; k < 16; k++) s += sf[k];
      s_fbc = s;
    }
    __syncthreads();
    sum_all = s_fbc;
  }

  // radix-select the TOPK-th largest over top-15 float bits (nonneg values)
  unsigned sel = 0u;
  for (int bit = 30; bit >= 16; --bit) {
    unsigned cand = sel | (1u << bit);
    int c = 0;
#pragma unroll
    for (int j = 0; j < PER; j++) c += (__float_as_uint(d[j]) >= cand) ? 1 : 0;
    for (int off = 32; off > 0; off >>= 1) c += __shfl_down(c, off);
    if ((tid & 63) == 0) si[tid >> 6] = c;
    __syncthreads();
    if (tid == 0) {
      int s = 0;
#pragma unroll
      for (int k = 0; k < 16; k++) s += si[k];
      s_ibc = s;
    }
    __syncthreads();
    if (s_ibc >= TOPK) sel = cand;
  }

  // sum of strictly-greater values + count (full-precision compare)
  int cgt = 0;
  float sgt = 0.0f;
#pragma unroll
  for (int j = 0; j < PER; j++) {
    if (__float_as_uint(d[j]) > sel) { cgt++; sgt += d[j]; }
  }
  {
    float v = sgt;
    for (int off = 32; off > 0; off >>= 1) v += __shfl_down(v, off);
    if ((tid & 63) == 0) sf[tid >> 6] = v;
    int c = cgt;
    for (int off = 32; off > 0; off >>= 1) c += __shfl_down(c, off);
    if ((tid & 63) == 0) si[tid >> 6] = c;
    __syncthreads();
    if (tid == 0) {
      float s = 0.0f;
      int cs = 0;
#pragma unroll
      for (int k = 0; k < 16; k++) { s += sf[k]; cs += si[k]; }
      float kth = __uint_as_float(sel);
      // exact under truncated pivot: subtracts/adds the tie overcount
      float topk_sum = s + (float)(TOPK - cs) * kth;
      float rowval = sum_all / (float)NPTS + 3.0f * (topk_sum / (float)TOPK);
      atomicAdd(out, rowval * (1.0f / (float)BATCH));
    }
  }
}

extern "C" void kernel_launch(void* const* d_in, const int* in_sizes, int n_in,
                              void* d_out, int out_size, void* d_ws, size_t ws_size,
                              hipStream_t stream) {
  const float* pred = (const float*)d_in[0];
  const float* gt   = (const float*)d_in[1];
  float* out = (float*)d_out;
  float* minsq = (float*)d_ws;   // [NROW][2][NPTS] = 512 KB

  dim3 gridA(NPTS / 64, 2, NROW);   // 2048 blocks -> 8/CU
  nn_min_kernel<<<gridA, BT, 0, stream>>>(pred, gt, minsq, out);
  select_kernel<<<NROW, BTB, 0, stream>>>(minsq, out);
}

// Round 9
// 78.355 us; speedup vs baseline: 4.3401x; 1.0533x over previous
//
#include <hip/hip_runtime.h>

// Chamfer loss: pred [8,4096,3] f32, gt [8,4096,3] f32 -> scalar f32.
//
// Budget (R11 measurement + R12 result): fill ~43us + harness reset
// dispatches ~21us (both fixed) + A ~13us + B ~4us. R11 counters for A:
// MfmaUtil 18%, VALUBusy 48% -> pipes sum ~6us, bubble ~7us. R13's
// 32x32x8 swap FAILED numerically (absmax 0.078, mechanism unidentified
// remotely) AND was mistargeted (matrix pipe at 18% has 5x headroom).
// R14 = R12's proven 32x32x16 kernel + bubble-only changes, arithmetic
// bit-identical:
//  1. uniform B addressing: all 64 lanes read the same LDS addresses
//     (broadcast, conflict-free); lanes>=32 feed B k=8..15 which multiply
//     A rows that are zero -> exact +0.0. Removes cndmask off/step setup
//     and zero-region staging.
//  2. 2-deep ds_read prefetch (~128cy lead vs ~120cy LDS latency); the
//     final over-reads land inside the 17408-B union (verified exact
//     bound) and are never consumed.
//  3. epilogue (LDS-transpose + register tree) and kernel B identical
//     to R12 (passed, absmax 0.0078).

#define BATCH 8
#define NPTS  4096
#define NPTS2 2048             // g-points per A-block (half the set)
#define TOPK  2048
#define BT    256
#define BTB   1024
#define NROW  (2 * BATCH)      // 16 rows = b*2+dir

typedef _Float16 half8 __attribute__((ext_vector_type(8)));
typedef float floatx16 __attribute__((ext_vector_type(16)));

static __device__ inline unsigned pack_h2(float a, float b) {
  unsigned short ua = __builtin_bit_cast(unsigned short, (_Float16)a);
  unsigned short ub = __builtin_bit_cast(unsigned short, (_Float16)b);
  return (unsigned)ua | ((unsigned)ub << 16);
}

static __device__ inline float amin3(float a, float b, float c) {
  float d;
  asm("v_min3_f32 %0, %1, %2, %3" : "=v"(d) : "v"(a), "v"(b), "v"(c));
  return d;
}

// ---------------- Kernel A: min squared distance via 32x32x16 MFMA ---------
// grid (64, 2, 16) = 2048 blocks -> 8 blocks/CU. Block: 64 q x 2048 g.
// Wave: 32 q x 1024 g (16 paired iterations).
__global__ __launch_bounds__(BT, 8) void nn_min_kernel(
    const float* __restrict__ pred, const float* __restrict__ gt,
    float* __restrict__ minsq, float* __restrict__ out) {
  const int row  = blockIdx.z;         // b*2 + dir
  const int half = blockIdx.y;         // which 2048 g-points
  const int b    = row >> 1;
  const int dir  = row & 1;
  const float* q = (dir == 0 ? pred : gt) + (size_t)b * NPTS * 3;
  const float* g = (dir == 0 ? gt : pred) + (size_t)b * NPTS * 3 +
                   (size_t)half * NPTS2 * 3;

  // gsh: staged f16x4 g-points (16384 B), dead after main loop.
  // scr: per-pair transpose scratch [pair][q 0..31][col 0..63 pad->68]
  // (17408 B) -> union size 17408 B. Separated by a barrier.
  union __align__(16) SharedU {
    uint2 gsh[NPTS2];
    float scr[2][32][68];
  };
  __shared__ SharedU sh;
  const int tid = threadIdx.x;

  // Stage 2048 g-points: 4 pts/thread/chunk via 3x float4 loads -> 2x b128.
#pragma unroll
  for (int c = 0; c < 2; c++) {
    int p = c * 1024 + tid * 4;                      // 4 consecutive points
    const float4* src = (const float4*)(g + 3 * p);  // 12 floats, 16B-aligned
    float4 f0 = src[0], f1 = src[1], f2 = src[2];
    float x0 = f0.x, y0 = f0.y, z0 = f0.z;
    float x1 = f0.w, y1 = f1.x, z1 = f1.y;
    float x2 = f1.z, y2 = f1.w, z2 = f2.x;
    float x3 = f2.y, y3 = f2.z, z3 = f2.w;
    uint2 u0 = make_uint2(pack_h2(-2.f * x0, -2.f * y0),
                          pack_h2(-2.f * z0, x0 * x0 + y0 * y0 + z0 * z0));
    uint2 u1 = make_uint2(pack_h2(-2.f * x1, -2.f * y1),
                          pack_h2(-2.f * z1, x1 * x1 + y1 * y1 + z1 * z1));
    uint2 u2 = make_uint2(pack_h2(-2.f * x2, -2.f * y2),
                          pack_h2(-2.f * z2, x2 * x2 + y2 * y2 + z2 * z2));
    uint2 u3 = make_uint2(pack_h2(-2.f * x3, -2.f * y3),
                          pack_h2(-2.f * z3, x3 * x3 + y3 * y3 + z3 * z3));
    *(uint4*)&sh.gsh[p]     = make_uint4(u0.x, u0.y, u1.x, u1.y);
    *(uint4*)&sh.gsh[p + 2] = make_uint4(u2.x, u2.y, u3.x, u3.y);
  }
  if (tid == 0 && blockIdx.x == 0 && blockIdx.y == 0 && blockIdx.z == 0)
    out[0] = 0.0f;                     // select accumulates into out

  const int lane = tid & 63;
  const int wave = tid >> 6;
  const int col  = lane & 31;          // n (g) index within tile
  const int hi   = lane >> 5;          // k-half / row-half selector
  const int pair = wave >> 1;                      // q-group pair id
  const int qg   = blockIdx.x * 2 + pair;          // q-group of 32
  const int gh   = wave & 1;                       // g-sub-half (1024 pts)
  const int q0   = qg * 32;

  // A fragment: lane l<32 holds A[m=l][k=0..7] = (qx,qy,qz,1,0,0,0,0);
  // lanes>=32 (k=8..15 rows) are zero -> their B operand x 0 = exact +0.
  half8 afrag = {};
  float qnv = 0.0f;
  if (lane < 32) {
    int qi = q0 + lane;
    float qx = q[3 * qi + 0], qy = q[3 * qi + 1], qz = q[3 * qi + 2];
    qnv = qx * qx + qy * qy + qz * qz;
    afrag[0] = (_Float16)qx;
    afrag[1] = (_Float16)qy;
    afrag[2] = (_Float16)qz;
    afrag[3] = (_Float16)1.0f;
  }
  __syncthreads();

  // Uniform addressing for ALL 64 lanes (lanes>=32 broadcast-read the same
  // addresses as lanes<32; their products are A-zeroed in the MFMA).
  const char* lds = (const char*)sh.gsh;
  int off = gh * 8192 + col * 8;

  float macc[16];
  floatx16 zc;
#pragma unroll
  for (int i = 0; i < 16; i++) { macc[i] = 3.0e38f; zc[i] = 0.0f; }

  // 32 g-tiles of 32, paired; ds_read prefetch 2 iterations (~128cy) ahead.
  // Deepest prefetch address: gh=1,col=31,t=15 -> 17400+8 = 17408 B =
  // exactly the union size (in-bounds); those values are never consumed.
  uint2 w0 = *(const uint2*)(lds + off);
  uint2 w1 = *(const uint2*)(lds + off + 256);
  uint2 w2 = *(const uint2*)(lds + off + 512);
  uint2 w3 = *(const uint2*)(lds + off + 768);
  off += 1024;
#pragma unroll 4
  for (int t = 0; t < 16; t++) {
    uint2 n0 = *(const uint2*)(lds + off);        // loads for t+2, issued
    uint2 n1 = *(const uint2*)(lds + off + 256);  // before the MFMA block
    off += 512;
    union { int4 i; half8 h; } b0, b1;
    b0.i = make_int4((int)w0.x, (int)w0.y, 0, 0);
    b1.i = make_int4((int)w1.x, (int)w1.y, 0, 0);
    floatx16 r0 = __builtin_amdgcn_mfma_f32_32x32x16_f16(afrag, b0.h, zc, 0, 0, 0);
    floatx16 r1 = __builtin_amdgcn_mfma_f32_32x32x16_f16(afrag, b1.h, zc, 0, 0, 0);
#pragma unroll
    for (int i = 0; i < 16; i++)
      macc[i] = amin3(macc[i], r0[i], r1[i]);
    w0 = w2; w1 = w3; w2 = n0; w3 = n1;
  }

  // -------- epilogue: LDS transpose + register tree (no butterfly) --------
  __syncthreads();                     // all main loops done; gsh dead

  // C/D layout: col=lane&31 (g), q-row=(i&3)+8*(i>>2)+4*hi. Write the
  // pair's 32x64 min-matrix: scr[pair][qrow][col + 32*gh]. Banks: rows q
  // and q+4 disjoint -> 2 touches/bank = free.
#pragma unroll
  for (int i = 0; i < 16; i++) {
    int qrow = (i & 3) + 8 * (i >> 2) + 4 * hi;
    sh.scr[pair][qrow][col + 32 * gh] = macc[i];
  }
  __syncthreads();

  // Even wave of each pair reduces its 32 rows over 64 cols and stores.
  if (gh == 0) {
    const int r = lane & 31;           // q-row handled by this lane
    const int h = lane >> 5;           // which 32-col half
    const float4* rp = (const float4*)&sh.scr[pair][r][h * 32];
    float4 m4 = rp[0];
#pragma unroll
    for (int k = 1; k < 8; k++) {
      float4 a = rp[k];
      m4.x = fminf(m4.x, a.x); m4.y = fminf(m4.y, a.y);
      m4.z = fminf(m4.z, a.z); m4.w = fminf(m4.w, a.w);
    }
    float m = fminf(amin3(m4.x, m4.y, m4.z), m4.w);
    m = fminf(m, __shfl_xor(m, 32));   // combine the two col-halves
    if (h == 0) {
      // lane r owns q-row r: qnv is this lane's own exact fp32 |q|^2
      minsq[((size_t)row * 2 + half) * NPTS + q0 + r] = fmaxf(qnv + m, 0.0f);
    }
  }
}

// ---------------- Kernel B: min-combine halves, sqrt, mean, top-k ----------
// block = 1024 (PER=4); 15-round radix on bits 30..16 (truncated-pivot-exact
// tie formula). 16 blocks, one per row.
__global__ __launch_bounds__(BTB) void select_kernel(
    const float* __restrict__ minsq, float* __restrict__ out) {
  const int row = blockIdx.x;                // 0..15 = b*2+dir
  const float* h0 = minsq + (size_t)row * 2 * NPTS;
  const float* h1 = h0 + NPTS;
  const int tid = threadIdx.x;

  __shared__ float sf[16];
  __shared__ int   si[16];
  __shared__ float s_fbc;
  __shared__ int   s_ibc;

  const int PER = NPTS / BTB;  // 4 values per thread
  float d[PER];
  float sum_all = 0.0f;
#pragma unroll
  for (int j = 0; j < PER; j++) {
    int idx = tid + BTB * j;
    float v = sqrtf(fminf(h0[idx], h1[idx]));
    d[j] = v;
    sum_all += v;
  }

  // block float sum of sum_all
  {
    float v = sum_all;
    for (int off = 32; off > 0; off >>= 1) v += __shfl_down(v, off);
    if ((tid & 63) == 0) sf[tid >> 6] = v;
    __syncthreads();
    if (tid == 0) {
      float s = 0.0f;
#pragma unroll
      for (int k = 0; k < 16; k++) s += sf[k];
      s_fbc = s;
    }
    __syncthreads();
    sum_all = s_fbc;
  }

  // radix-select the TOPK-th largest over top-15 float bits (nonneg values)
  unsigned sel = 0u;
  for (int bit = 30; bit >= 16; --bit) {
    unsigned cand = sel | (1u << bit);
    int c = 0;
#pragma unroll
    for (int j = 0; j < PER; j++) c += (__float_as_uint(d[j]) >= cand) ? 1 : 0;
    for (int off = 32; off > 0; off >>= 1) c += __shfl_down(c, off);
    if ((tid & 63) == 0) si[tid >> 6] = c;
    __syncthreads();
    if (tid == 0) {
      int s = 0;
#pragma unroll
      for (int k = 0; k < 16; k++) s += si[k];
      s_ibc = s;
    }
    __syncthreads();
    if (s_ibc >= TOPK) sel = cand;
  }

  // sum of strictly-greater values + count (full-precision compare)
  int cgt = 0;
  float sgt = 0.0f;
#pragma unroll
  for (int j = 0; j < PER; j++) {
    if (__float_as_uint(d[j]) > sel) { cgt++; sgt += d[j]; }
  }
  {
    float v = sgt;
    for (int off = 32; off > 0; off >>= 1) v += __shfl_down(v, off);
    if ((tid & 63) == 0) sf[tid >> 6] = v;
    int c = cgt;
    for (int off = 32; off > 0; off >>= 1) c += __shfl_down(c, off);
    if ((tid & 63) == 0) si[tid >> 6] = c;
    __syncthreads();
    if (tid == 0) {
      float s = 0.0f;
      int cs = 0;
#pragma unroll
      for (int k = 0; k < 16; k++) { s += sf[k]; cs += si[k]; }
      float kth = __uint_as_float(sel);
      // exact under truncated pivot: corrects the tie overcount
      float topk_sum = s + (float)(TOPK - cs) * kth;
      float rowval = sum_all / (float)NPTS + 3.0f * (topk_sum / (float)TOPK);
      atomicAdd(out, rowval * (1.0f / (float)BATCH));
    }
  }
}

extern "C" void kernel_launch(void* const* d_in, const int* in_sizes, int n_in,
                              void* d_out, int out_size, void* d_ws, size_t ws_size,
                              hipStream_t stream) {
  const float* pred = (const float*)d_in[0];
  const float* gt   = (const float*)d_in[1];
  float* out = (float*)d_out;
  float* minsq = (float*)d_ws;   // [NROW][2][NPTS] = 512 KB

  dim3 gridA(NPTS / 64, 2, NROW);   // 2048 blocks -> 8/CU
  nn_min_kernel<<<gridA, BT, 0, stream>>>(pred, gt, minsq, out);
  select_kernel<<<NROW, BTB, 0, stream>>>(minsq, out);
}